// Round 7
// baseline (752.649 us; speedup 1.0000x reference)
//
#include <hip/hip_runtime.h>
#include <hip/hip_bf16.h>
#include <hip/hip_fp16.h>

#define H 2048
#define E 8
#define DFF 8192
#define NTOK 4096
#define NB 4  // H/512 scale blocks

typedef _Float16 f16x8 __attribute__((ext_vector_type(8)));
typedef _Float16 f16x2 __attribute__((ext_vector_type(2)));
typedef float f32x4 __attribute__((ext_vector_type(4)));

#define AS1 __attribute__((address_space(1)))
#define AS3 __attribute__((address_space(3)))

__device__ __forceinline__ void gl_lds16(const void* g, void* l) {
    __builtin_amdgcn_global_load_lds((const AS1 unsigned int*)g,
                                     (AS3 unsigned int*)l, 16, 0, 0);
}

__device__ __forceinline__ float gelu_f(float x) {
    float u = 0.7978845608028654f * x * (1.0f + 0.044715f * x * x);
    float t = fabsf(u);
    float e = __expf(-2.0f * t);
    float th = (1.0f - e) / (1.0f + e);
    th = copysignf(th, u);
    return 0.5f * x * (1.0f + th);
}

// ------- fused router (fp32) + x->fp16 cast + NF4 dequant expert mix -------
__global__ __launch_bounds__(256) void router_moe_kernel(
    const float* __restrict__ x, const float* __restrict__ rw,
    const int* __restrict__ nf4, const float* __restrict__ mean,
    const float* __restrict__ stdv, const float* __restrict__ cb,
    _Float16* __restrict__ xh, float* __restrict__ moe)
{
    int n = blockIdx.x, t = threadIdx.x;
    __shared__ float red[4][E];
    __shared__ float pr[E];
    __shared__ float cbl[32];       // 2 copies of 16-entry codebook
    __shared__ float ps[E][NB];     // prob*std
    __shared__ float cmean[NB];     // sum_e prob*mean

    // ---- phase 1: router dot + cast ----
    float acc[E];
#pragma unroll
    for (int e = 0; e < E; ++e) acc[e] = 0.f;
    const float* xr = x + (size_t)n * H;
#pragma unroll
    for (int k = 0; k < H / 256; ++k) {
        int h = t + k * 256;
        float xv = xr[h];
        xh[(size_t)n * H + h] = (_Float16)xv;
        const float4* r4 = reinterpret_cast<const float4*>(rw + (size_t)h * E);
        float4 a = r4[0], b = r4[1];
        acc[0] += xv * a.x; acc[1] += xv * a.y; acc[2] += xv * a.z; acc[3] += xv * a.w;
        acc[4] += xv * b.x; acc[5] += xv * b.y; acc[6] += xv * b.z; acc[7] += xv * b.w;
    }
#pragma unroll
    for (int e = 0; e < E; ++e) {
        float v = acc[e];
#pragma unroll
        for (int o = 32; o > 0; o >>= 1) v += __shfl_down(v, o, 64);
        acc[e] = v;
    }
    int wave = t >> 6, lane = t & 63;
    if (lane == 0) {
#pragma unroll
        for (int e = 0; e < E; ++e) red[wave][e] = acc[e];
    }
    __syncthreads();
    if (t == 0) {
        float lg[E];
        float mx = -1e30f;
#pragma unroll
        for (int e = 0; e < E; ++e) {
            lg[e] = red[0][e] + red[1][e] + red[2][e] + red[3][e];
            mx = fmaxf(mx, lg[e]);
        }
        float s = 0.f;
#pragma unroll
        for (int e = 0; e < E; ++e) { lg[e] = expf(lg[e] - mx); s += lg[e]; }
        float inv = 1.f / s;
#pragma unroll
        for (int e = 0; e < E; ++e) {
            float p = lg[e] * inv;
            pr[e] = __half2float(__float2half(p));   // fp16 round-trip
        }
    }
    __syncthreads();

    // ---- phase 2: per-block scale tables ----
    if (t < 16) { float v = cb[t]; cbl[t] = v; cbl[t + 16] = v; }
    else if (t >= 32 && t < 64) {
        int e = (t - 32) >> 2, b = t & 3;
        ps[e][b] = pr[e] * stdv[((size_t)n * E + e) * NB + b];
    } else if (t >= 64 && t < 68) {
        int b = t - 64; float s = 0.f;
        for (int e = 0; e < E; ++e)
            s += pr[e] * mean[((size_t)n * E + e) * NB + b];
        cmean[b] = s;
    }
    __syncthreads();

    // ---- phase 3: NF4 mix, int4 loads (4 words -> 8 h values / thread) ----
    int b = t >> 6;                 // h-block index, wave-uniform
    int cboff = (t & 1) << 4;
    const int4* w4 = reinterpret_cast<const int4*>(nf4 + (size_t)n * (E * H / 2));
    float o[8];
    float cm = cmean[b];
#pragma unroll
    for (int u = 0; u < 8; ++u) o[u] = cm;
#pragma unroll
    for (int e = 0; e < E; ++e) {
        int4 wv = w4[e * 256 + t];
        float pse = ps[e][b];
        int w0 = wv.x, w1 = wv.y, w2 = wv.z, w3 = wv.w;
        o[0] += pse * cbl[(w0 & 15) + cboff];
        o[1] += pse * cbl[((w0 >> 4) & 15) + cboff];
        o[2] += pse * cbl[(w1 & 15) + cboff];
        o[3] += pse * cbl[((w1 >> 4) & 15) + cboff];
        o[4] += pse * cbl[(w2 & 15) + cboff];
        o[5] += pse * cbl[((w2 >> 4) & 15) + cboff];
        o[6] += pse * cbl[(w3 & 15) + cboff];
        o[7] += pse * cbl[((w3 >> 4) & 15) + cboff];
    }
    float4* op = reinterpret_cast<float4*>(moe + (size_t)n * H + 8 * t);
    op[0] = make_float4(o[0], o[1], o[2], o[3]);
    op[1] = make_float4(o[4], o[5], o[6], o[7]);
}

// ------- fused dual transpose + cast: w1 [H,DFF]->[DFF,H], w2 [DFF,H]->[H,DFF]
// 64x64 tiles, float4 loads, f16x2 writes; one dispatch for both matrices.
__global__ __launch_bounds__(256) void transpose2_kernel(
    const float* __restrict__ w1, const float* __restrict__ w2,
    _Float16* __restrict__ w1t, _Float16* __restrict__ w2t)
{
    __shared__ float tile[64][65];
    int id = blockIdx.x;
    const float* src; _Float16* dst; int R, C, bx, by;
    if (id < (DFF / 64) * (H / 64)) {
        src = w1; dst = w1t; R = H; C = DFF;
        bx = id % (DFF / 64); by = id / (DFF / 64);
    } else {
        id -= (DFF / 64) * (H / 64);
        src = w2; dst = w2t; R = DFF; C = H;
        bx = id % (H / 64); by = id / (H / 64);
    }
    int t = threadIdx.x;
    int c0 = bx * 64, r0 = by * 64;
    int ct = (t & 15) * 4, rt = t >> 4;
#pragma unroll
    for (int i = 0; i < 4; ++i) {
        int r = rt + i * 16;
        float4 v = *reinterpret_cast<const float4*>(src + (size_t)(r0 + r) * C + c0 + ct);
        tile[r][ct] = v.x; tile[r][ct + 1] = v.y;
        tile[r][ct + 2] = v.z; tile[r][ct + 3] = v.w;
    }
    __syncthreads();
    int u = (t & 31) * 2, cq = t >> 5;
#pragma unroll
    for (int i = 0; i < 8; ++i) {
        int c = cq + i * 8;
        f16x2 pk;
        pk[0] = (_Float16)tile[u][c];
        pk[1] = (_Float16)tile[u + 1][c];
        *reinterpret_cast<f16x2*>(dst + (size_t)(c0 + c) * R + r0 + u) = pk;
    }
}

// ---- fp16 MFMA GEMM: 256x256, BK=32, 5-buffer pipeline, compiler-woven ----
// C = A[M,K] * Bt[N,K]^T.  512 thr / 8 waves (2M x 4N, per-wave 128x64,
// acc[8][4]).  BK=32 tile buffer = 32 KB; FIVE rotating buffers (160 KB).
// k-seg-major layout (conflict-free; per-lane GLOBAL address provides the
// permutation, global_load_lds writes linearly).
// KEY CHANGE vs rounds 1-6: NO manual lgkmcnt(0), NO sched_barrier, NO
// setprio inside the tile body.  Reads, stage-issues and MFMAs appear in
// plain dependency order; the compiler emits fine-grained COUNTED lgkmcnt
// and interleaves ds_read with MFMA (m97 evidence: this weave is what the
// hand-scheduled variants were suppressing -> CU ping-ponged between an
// all-LDS burst and an all-MFMA burst, ~2050 cyc/tile vs ~1150 LDS /
// ~1024 MFMA pipe floors).  One barrier per tile; counted vmcnt(8) keeps
// 2 tiles (8 loads) permanently in flight; stage targets t+3 whose buffer
// was last read at t-2 (>=2 barriers separation).
// EPI 0: out = f16(gelu(acc)).
// EPI 1: split-K pair: ks==0 -> out = acc + addsrc; ks==1 -> aux = acc.
template <int EPI, int MAP>
__global__ __launch_bounds__(512, 2) void gemmW_kernel(
    const _Float16* __restrict__ A, const _Float16* __restrict__ Bt,
    const float* __restrict__ addsrc, void* __restrict__ outv,
    float* __restrict__ aux, int K, int LDK, int N)
{
    __shared__ uint4 lds_u4[163840 / 16];   // 160 KB = 5 x 32 KB
    char* lds = (char*)lds_u4;

    int t = threadIdx.x;
    int id = blockIdx.x;
    int xcd = id & 7, chunk = id >> 3;
    int by, bx, ks = 0;
    if constexpr (MAP == 0) {
        by = (xcd & 1) * 8 + (chunk & 7);
        bx = (xcd >> 1) * 8 + (chunk >> 3);
    } else {
        by = (xcd >> 1) * 4 + (chunk & 3);
        bx = (xcd & 1) * 4 + ((chunk >> 2) & 3);
        ks = chunk >> 4;
    }
    int m0 = by * 256, n0 = bx * 256;
    int koff = ks * K;

    // staging sources: thread t -> row (t&255), kseg (t>>8) of the tile
    const unsigned short* sA = (const unsigned short*)A
        + (size_t)(m0 + (t & 255)) * LDK + koff + (t >> 8) * 8;
    const unsigned short* sB = (const unsigned short*)Bt
        + (size_t)(n0 + (t & 255)) * LDK + koff + (t >> 8) * 8;
    unsigned dstT = (unsigned)t * 16;

    int lane = t & 63, wave = t >> 6;
    int wr = wave >> 2, wc = wave & 3;      // 2M x 4N
    int mb = wr * 128, nb = wc * 64;
    int q = lane >> 4, m16 = lane & 15;

    // LDS read offsets within a 32 KB buffer: A at 0, B at 16384;
    // addr = region + kseg(q)*4096 + row*16
    unsigned aOff = (unsigned)(q * 4096 + (mb + m16) * 16);
    unsigned bOff = (unsigned)(16384 + q * 4096 + (nb + m16) * 16);

    f32x4 acc[8][4] = {};
    f16x8 afL[4], afH[4], bf[4];

#define STG_A(Wb, T) do { \
    gl_lds16(sA + (size_t)(T) * 32,      (Wb) + dstT); \
    gl_lds16(sA + (size_t)(T) * 32 + 16, (Wb) + 8192 + dstT); } while (0)
#define STG_B(Wb, T) do { \
    gl_lds16(sB + (size_t)(T) * 32,      (Wb) + 16384 + dstT); \
    gl_lds16(sB + (size_t)(T) * 32 + 16, (Wb) + 16384 + 8192 + dstT); } while (0)
#define RD_B(Rb) do { \
    _Pragma("unroll") for (int jl = 0; jl < 4; ++jl) \
        bf[jl] = *(const f16x8*)((Rb) + bOff + jl * 256); } while (0)
#define RD_AL(Rb) do { \
    _Pragma("unroll") for (int il = 0; il < 4; ++il) \
        afL[il] = *(const f16x8*)((Rb) + aOff + il * 256); } while (0)
#define RD_AH(Rb) do { \
    _Pragma("unroll") for (int il = 0; il < 4; ++il) \
        afH[il] = *(const f16x8*)((Rb) + aOff + 1024 + il * 256); } while (0)
#define MM(i0, afr) do { \
    _Pragma("unroll") for (int il = 0; il < 4; ++il) \
    _Pragma("unroll") for (int jl = 0; jl < 4; ++jl) \
        acc[(i0) + il][jl] = __builtin_amdgcn_mfma_f32_16x16x32_f16( \
            afr[il], bf[jl], acc[(i0) + il][jl], 0, 0, 0); } while (0)
#define BARR  asm volatile("s_barrier" ::: "memory")

    // prologue: stage tiles 0,1,2 -> bufs 0,1,2 (12 loads); drain tile 0
    STG_A(lds,         0); STG_B(lds,         0);
    STG_A(lds + 32768, 1); STG_B(lds + 32768, 1);
    STG_A(lds + 65536, 2); STG_B(lds + 65536, 2);
    asm volatile("s_waitcnt vmcnt(8)" ::: "memory");   // tile 0 landed
    BARR;

    int NT = K / 32;
    unsigned rb = 0, wb = 3 * 32768;
    for (int T = 0; T < NT; ++T) {
        char* R = lds + rb;
        char* W = lds + wb;
        bool st = (T + 3 < NT);

        // reads + stage-issues + MFMAs in dependency order; the compiler
        // weaves counted lgkmcnt and overlaps LDS pipe with MFMA pipe.
        RD_B(R);
        RD_AL(R);
        if (st) { STG_A(W, T + 3); STG_B(W, T + 3); }
        MM(0, afL);
        RD_AH(R);
        MM(4, afH);

        if (st) asm volatile("s_waitcnt vmcnt(8)" ::: "memory");  // t+1 landed
        else    asm volatile("s_waitcnt vmcnt(0)" ::: "memory");
        BARR;

        rb += 32768; if (rb == 163840) rb = 0;
        wb += 32768; if (wb == 163840) wb = 0;
    }

    // epilogue (verified C/D mapping: col=lane&15, row=q*4+rix)
#pragma unroll
    for (int i = 0; i < 8; ++i)
#pragma unroll
        for (int j = 0; j < 4; ++j) {
            int row = m0 + mb + i * 16 + q * 4;
            int col = n0 + nb + j * 16 + m16;
#pragma unroll
            for (int rix = 0; rix < 4; ++rix) {
                float v = acc[i][j][rix];
                size_t o = (size_t)(row + rix) * N + col;
                if constexpr (EPI == 0) {
                    ((_Float16*)outv)[o] = (_Float16)gelu_f(v);
                } else {
                    if (ks == 0) ((float*)outv)[o] = v + addsrc[o];
                    else         aux[o] = v;
                }
            }
        }
#undef STG_A
#undef STG_B
#undef RD_B
#undef RD_AL
#undef RD_AH
#undef MM
#undef BARR
}

// ---------------- split-K combine: out += part ----------------
__global__ __launch_bounds__(256) void combine_kernel(
    float* __restrict__ out, const float* __restrict__ part)
{
    size_t base = (size_t)blockIdx.x * 256 + threadIdx.x;
    const float4* p4 = (const float4*)part;
    float4* o4 = (float4*)out;
#pragma unroll
    for (int s = 0; s < 4; ++s) {
        size_t i = base + (size_t)s * 524288;   // 2048*256
        float4 a = o4[i], b = p4[i];
        o4[i] = make_float4(a.x + b.x, a.y + b.y, a.z + b.z, a.w + b.w);
    }
}

extern "C" void kernel_launch(void* const* d_in, const int* in_sizes, int n_in,
                              void* d_out, int out_size, void* d_ws, size_t ws_size,
                              hipStream_t stream) {
    const float* x    = (const float*)d_in[0];
    const float* rw   = (const float*)d_in[1];
    const int*   nf4  = (const int*)d_in[2];
    const float* mean = (const float*)d_in[3];
    const float* stdv = (const float*)d_in[4];
    const float* cb   = (const float*)d_in[5];
    const float* w1   = (const float*)d_in[6];
    const float* w2   = (const float*)d_in[7];
    float* out = (float*)d_out;

    char* ws = (char*)d_ws;
    float* moe        = (float*)(ws + 131072);               // 32 MB
    _Float16* xh      = (_Float16*)(ws + 33685504);          // 16 MB  [NTOK,H]
    _Float16* w1t     = (_Float16*)(ws + 50462720);          // 32 MB  [DFF,H]
    _Float16* w2t     = (_Float16*)(ws + 84017152);          // 32 MB  [H,DFF]
    _Float16* hid     = (_Float16*)(ws + 117571584);         // 64 MB  [NTOK,DFF]
    // split-K partial buffer overlays w1t (dead after GEMM1): 32 MB fp32
    float* pbuf       = (float*)(ws + 50462720);

    // fused router + cast + NF4 expert mix (probs stay in LDS)
    router_moe_kernel<<<NTOK, 256, 0, stream>>>(x, rw, nf4, mean, stdv, cb, xh, moe);
    // both weight transposes in one dispatch
    transpose2_kernel<<<2 * (DFF / 64) * (H / 64), 256, 0, stream>>>(w1, w2, w1t, w2t);
    // hidden = gelu(x @ w1): 256x256 tiles, grid 16x32 -> 512 blocks (2 rounds)
    gemmW_kernel<0, 0><<<512, 512, 0, stream>>>(xh, w1t, nullptr, (void*)hid,
                                                nullptr, H, H, DFF);
    // out = moe + hidden @ w2, split-K=2: 256 blocks (1/CU)
    gemmW_kernel<1, 1><<<256, 512, 0, stream>>>(hid, w2t, moe, (void*)out,
                                                pbuf, DFF / 2, DFF, H);
    // out += pbuf
    combine_kernel<<<2048, 256, 0, stream>>>(out, pbuf);
}